// Round 1
// baseline (884.154 us; speedup 1.0000x reference)
//
#include <hip/hip_runtime.h>
#include <stdint.h>

// 32768 samples, 4300 fp32 each. One thread per (sample,row): 20 rows/sample.
// 16 samples per block -> 320 threads (5 waves).
// Weights are wave-uniform -> read straight from global via the SCALAR path
// (s_load into SGPRs, v_fma with one SGPR operand). LDS holds only the
// per-sample activation mixing buffers (double-buffered, 1 barrier/GCN iter).

#define SPB 16           // samples per block
#define NT  (SPB * 20)   // 320 threads
#define ACT_STRIDE 164   // floats per sample slot: 164*4=656B -> bank shift 4, 16B aligned

struct P { const float* __restrict__ a[33]; float* __restrict__ out; };

template<int DIN, int DOUT, bool RELU>
__device__ __forceinline__ void lin(const float* in, float* out,
                                    const float* __restrict__ wgt,
                                    const float* __restrict__ bias) {
  #pragma unroll
  for (int j = 0; j < DOUT; ++j) {
    float acc = bias[j];
    #pragma unroll
    for (int k = 0; k < DIN; ++k) acc = fmaf(in[k], wgt[j * DIN + k], acc);
    out[j] = RELU ? fmaxf(acc, 0.0f) : acc;
  }
}

// out8[c] = sum_n coef[n] * act[n*8+c]
__device__ __forceinline__ void mix20(const float* coef, const float* actBase, float* out8) {
  #pragma unroll
  for (int c = 0; c < 8; ++c) out8[c] = 0.0f;
  #pragma unroll
  for (int n = 0; n < 20; ++n) {
    float g = coef[n];
    const float* ar = actBase + n * 8;
    #pragma unroll
    for (int c = 0; c < 8; ++c) out8[c] = fmaf(g, ar[c], out8[c]);
  }
}

// load 20 contiguous fp32 (16B-aligned) -> registers
__device__ __forceinline__ void load20(const float* p, float* o) {
  const float4* q = (const float4*)p;
  #pragma unroll
  for (int j = 0; j < 5; ++j) {
    float4 u = q[j];
    o[j*4+0] = u.x; o[j*4+1] = u.y; o[j*4+2] = u.z; o[j*4+3] = u.w;
  }
}

__global__ __launch_bounds__(NT) void marabou_fused(P p) {
  __shared__ float actA[SPB * ACT_STRIDE];
  __shared__ float actB[SPB * ACT_STRIDE];

  const int tid = threadIdx.x;
  const int sl = tid / 20;
  const int r  = tid - sl * 20;
  const long gs = (long)blockIdx.x * SPB + sl;
  const float* __restrict__ v = p.a[0] + gs * 4300;

  // named uniform weight/bias pointers (kernarg SGPRs -> s_load path)
  const float* __restrict__ H1W = p.a[1];  const float* __restrict__ H1B = p.a[2];
  const float* __restrict__ H2W = p.a[3];  const float* __restrict__ H2B = p.a[4];
  const float* __restrict__ H3W = p.a[5];  const float* __restrict__ H3B = p.a[6];
  const float* __restrict__ F1W = p.a[7];  const float* __restrict__ F1B = p.a[8];
  const float* __restrict__ F2W = p.a[9];  const float* __restrict__ F2B = p.a[10];
  const float* __restrict__ F3W = p.a[11]; const float* __restrict__ F3B = p.a[12];
  const float* __restrict__ D1W = p.a[13]; const float* __restrict__ D1B = p.a[14];
  const float* __restrict__ D2W = p.a[15]; const float* __restrict__ D2B = p.a[16];
  const float* __restrict__ D3W = p.a[17]; const float* __restrict__ D3B = p.a[18];
  const float* __restrict__ G1W = p.a[19]; const float* __restrict__ G1B = p.a[20];
  const float* __restrict__ G2W = p.a[21]; const float* __restrict__ G2B = p.a[22];
  const float* __restrict__ G3W = p.a[23]; const float* __restrict__ G3B = p.a[24];
  const float* __restrict__ C1W = p.a[25]; const float* __restrict__ C1B = p.a[26];
  const float* __restrict__ C2W = p.a[27]; const float* __restrict__ C2B = p.a[28];
  const float* __restrict__ C3W = p.a[29]; const float* __restrict__ C3B = p.a[30];
  const float* __restrict__ C4W = p.a[31]; const float* __restrict__ C4B = p.a[32];

  float* myA = actA + sl * ACT_STRIDE;
  float* myB = actB + sl * ACT_STRIDE;

  // node_inputs row (5)
  float ni[5];
  #pragma unroll
  for (int k = 0; k < 5; ++k) ni[k] = v[r * 5 + k];

  float t16[16], t8[8], xb[8], y[8];

  // h chain: 5->16->8->8
  lin<5, 16, true>(ni, t16, H1W, H1B);
  lin<16, 8, true>(t16, t8, H2W, H2B);
  lin<8, 8, true>(t8, xb, H3W, H3B);
  #pragma unroll
  for (int c = 0; c < 8; ++c) y[c] = xb[c];

  // 8 GCN iterations, double-buffered act -> ONE barrier per iteration.
  // Iter i writes+reads buf[i&1]; iter i-2's readers of the same buffer
  // finished before iter i-1's barrier, so no WAR hazard.
  for (int i = 0; i < 8; ++i) {
    // fblk #1
    lin<8, 16, true>(y, t16, F1W, F1B);
    lin<16, 8, true>(t16, t8, F2W, F2B);
    lin<8, 8, true>(t8, y, F3W, F3B);

    float* buf = (i & 1) ? myB : myA;
    #pragma unroll
    for (int c = 0; c < 8; ++c) buf[r * 8 + c] = y[c];

    float grow[20];
    load20(v + 120 + i * 400 + r * 20, grow);   // in flight across the barrier
    __syncthreads();                 // writes visible

    float ym[8];
    mix20(grow, buf, ym);            // y = gcn_mats[i] @ y

    // fblk #2
    lin<8, 16, true>(ym, t16, F1W, F1B);
    lin<16, 8, true>(t16, t8, F2W, F2B);
    lin<8, 8, true>(t8, y, F3W, F3B);

    #pragma unroll
    for (int c = 0; c < 8; ++c) y[c] += xb[c];   // residual
  }
  // last iteration (i=7) used myB; its reads completed before the next barrier.

  // d chain on [ni, y] (13 -> 16 -> 8 -> 8)
  float d13[13];
  #pragma unroll
  for (int k = 0; k < 5; ++k) d13[k] = ni[k];
  #pragma unroll
  for (int k = 0; k < 8; ++k) d13[5 + k] = y[k];
  float s8[8];
  lin<13, 16, true>(d13, t16, D1W, D1B);
  lin<16, 8, true>(t16, t8, D2W, D2B);
  lin<8, 8, true>(t8, s8, D3W, D3B);

  // write s8 -> A: prior A readers were iter 6's mix, done before iter 7's barrier
  #pragma unroll
  for (int c = 0; c < 8; ++c) myA[r * 8 + c] = s8[c];
  float srow[20];
  load20(v + 3480 + r * 20, srow);
  __syncthreads();

  float dag[8];
  mix20(srow, myA, dag);             // dag_summary = summ_mats @ s

  // stash dag rows in B: prior B readers (iter 7 mix) finished before the barrier above
  #pragma unroll
  for (int c = 0; c < 8; ++c) myB[r * 8 + c] = dag[c];

  // g chain 8->16->8->8 (per-row)
  float g3r[8];
  lin<8, 16, true>(dag, t16, G1W, G1B);
  lin<16, 8, true>(t16, t8, G2W, G2B);
  lin<8, 8, true>(t8, g3r, G3W, G3B);

  __syncthreads();                   // summ-mix A reads done; dag B writes visible
  #pragma unroll
  for (int c = 0; c < 8; ++c) myA[r * 8 + c] = g3r[c];
  float runrow[20];
  load20(v + 3880, runrow);
  float brow[20];
  load20(v + 3900 + r * 20, brow);
  __syncthreads();

  // global_summary = running @ g3   (all rows compute same result, fine)
  float glob[8];
  mix20(runrow, myA, glob);

  // dag_extend = back_map @ dag_summary
  float dext[8];
  mix20(brow, myB, dext);

  // merge (29) -> fc chain 29->32->16->8->1
  float m29[29];
  #pragma unroll
  for (int k = 0; k < 5; ++k) m29[k] = ni[k];
  #pragma unroll
  for (int k = 0; k < 8; ++k) m29[5 + k] = y[k];
  #pragma unroll
  for (int k = 0; k < 8; ++k) m29[13 + k] = dext[k];
  #pragma unroll
  for (int k = 0; k < 8; ++k) m29[21 + k] = glob[k];

  float a32[32];
  lin<29, 32, true>(m29, a32, C1W, C1B);
  lin<32, 16, true>(a32, t16, C2W, C2B);
  lin<16, 8, true>(t16, t8, C3W, C3B);

  float o = C4B[0];                  // fc4 bias
  #pragma unroll
  for (int k = 0; k < 8; ++k) o = fmaf(t8[k], C4W[k], o);

  float mask = v[100 + r];
  o += mask * 10000.0f;

  p.out[gs * 20 + r] = o;
}

extern "C" void kernel_launch(void* const* d_in, const int* in_sizes, int n_in,
                              void* d_out, int out_size, void* d_ws, size_t ws_size,
                              hipStream_t stream) {
  P p;
  for (int i = 0; i < 33; ++i) p.a[i] = (const float*)d_in[i];
  p.out = (float*)d_out;

  const int B = in_sizes[0] / 4300;      // 32768
  const int nblocks = (B + SPB - 1) / SPB;
  marabou_fused<<<nblocks, NT, 0, stream>>>(p);
}